// Round 19
// baseline (129.658 us; speedup 1.0000x reference)
//
#include <hip/hip_runtime.h>
#include <stdint.h>

typedef __attribute__((ext_vector_type(8))) short bf16x8;
typedef __attribute__((ext_vector_type(4))) float f32x4;

__device__ __forceinline__ uint32_t f2bf(float f) {
    uint32_t u = __builtin_bit_cast(uint32_t, f);
    u += 0x7fffu + ((u >> 16) & 1u);   // RNE round to bf16
    return u >> 16;
}
__device__ __forceinline__ uint32_t pack2(float a, float b) {
    return f2bf(a) | (f2bf(b) << 16);
}

// Fused prep: fp32 [rows][128] -> bf16 fragment order AND reciprocal norms.
__global__ __launch_bounds__(256) void prep_all(const float* __restrict__ qe,
                                                const float* __restrict__ pe,
                                                unsigned short* __restrict__ Qf,
                                                unsigned short* __restrict__ Pf,
                                                float* __restrict__ rq,
                                                float* __restrict__ rp,
                                                int qgroups) {
    __shared__ float part[16][17];
    const int gi = blockIdx.x;
    const int rem = threadIdx.x;
    const bool isQ = gi < qgroups;
    const int g = isQ ? gi : gi - qgroups;
    const float* src = isQ ? qe : pe;
    unsigned short* dst = isQ ? Qf : Pf;

    const int c = rem >> 6, lane = rem & 63;
    const int rowl = lane & 15;
    const int hi = lane >> 4;
    const int row = g * 16 + rowl;
    const int col = c * 32 + hi * 8;
    const float* s = src + (size_t)row * 128 + col;
    float4 a0 = *(const float4*)s;
    float4 a1 = *(const float4*)(s + 4);
    uint4 pk = { pack2(a0.x, a0.y), pack2(a0.z, a0.w),
                 pack2(a1.x, a1.y), pack2(a1.z, a1.w) };
    *(uint4*)(dst + ((size_t)g * 256 + rem) * 8) = pk;

    float ssq = a0.x*a0.x + a0.y*a0.y + a0.z*a0.z + a0.w*a0.w
              + a1.x*a1.x + a1.y*a1.y + a1.z*a1.z + a1.w*a1.w;
    part[rowl][c * 4 + hi] = ssq;
    __syncthreads();
    if (rem < 16) {
        float s16 = 0.f;
#pragma unroll
        for (int j = 0; j < 16; ++j) s16 += part[rem][j];
        float r = 1.0f / fmaxf(sqrtf(s16), 1e-8f);
        (isQ ? rq : rp)[g * 16 + rem] = r;
    }
}

// xor streamer: R14 verbatim (linear walk, 1KB/wave-instr NT stores, ~6.5 TB/s).
__global__ __launch_bounds__(256) void xor_stream(const int* __restrict__ qid,
                                                  const int* __restrict__ pid,
                                                  float* __restrict__ oxor,
                                                  int total4, int pmask_log2) {
    const int stride = gridDim.x * 256;
    int idx = blockIdx.x * 256 + threadIdx.x;
    const int pmask = (1 << pmask_log2) - 1;
    for (; idx < total4; idx += stride) {
        const int q = idx >> pmask_log2;
        const int pi = (idx & pmask) << 2;
        const int qv = qid[q];
        const int4 pv = *(const int4*)(pid + pi);
        f32x4 x = { pv.x == qv ? 1.f : 0.f, pv.y == qv ? 1.f : 0.f,
                    pv.z == qv ? 1.f : 0.f, pv.w == qv ? 1.f : 0.f };
        __builtin_nontemporal_store(x, (f32x4*)(oxor + ((size_t)idx << 2)));
    }
}

#define PBLK 2048   // p extent per block

// cos GEMM v19: compute identical to R18 (wave stages 16q x 256p bf16 in its
// slice). NEW: flush ownership transposed -- after a barrier, wave w writes
// rows w*4..w*4+3 across ALL FOUR slices: each row = 4 back-to-back 1KB NT
// stores = 4KB CONTIGUOUS RUN, extended sequentially by the next round
// (8KB linear per row per block). Attacks DRAM page-activation overhead.
__global__ __launch_bounds__(256, 4) void cos_gemm(
        const unsigned short* __restrict__ Qf, const unsigned short* __restrict__ Pf,
        const float* __restrict__ rq, const float* __restrict__ rp,
        float* __restrict__ ocos, int Pn) {
    __shared__ __align__(16) unsigned short sc[4][16][264];   // 33KB

    const int nwg = gridDim.x;
    const int chunk = nwg >> 3;
    const int bid = blockIdx.x;
    const int wg = (bid & 7) * chunk + (bid >> 3);   // bijective XCD chunking
    const int nPc = Pn / PBLK;
    const int qg = wg / nPc;
    const int pc = wg % nPc;
    const int pblock = pc * PBLK;

    const int t = threadIdx.x;
    const int lane = t & 63;
    const int w = t >> 6;
    const int lq = lane & 15;
    const int g4 = (lane >> 4) << 2;   // 0,4,8,12

    // A fragments: coalesced 1KB loads
    bf16x8 af[4];
    const unsigned short* abase = Qf + (size_t)qg * 2048 + lane * 8;
#pragma unroll
    for (int kk = 0; kk < 4; ++kk)
        af[kk] = *(const bf16x8*)(abase + kk * 512);

    const int qrow_base = qg * 16;
    const float rqv = rq[qrow_base + lq];

#pragma unroll 1
    for (int fl = 0; fl < PBLK / 1024; ++fl) {       // 2 rounds
        const int pw = pblock + fl * 1024 + w * 256; // wave's compute 256p span
        // ---- compute 16 fragments; stage bf16 into this wave's slice ----
#pragma unroll 4
        for (int f = 0; f < 16; ++f) {
            const int p0 = pw + f * 16;
            const unsigned short* bbase = Pf + (size_t)(p0 >> 4) * 2048 + (size_t)lane * 8;
            bf16x8 bfr[4];
#pragma unroll
            for (int kk = 0; kk < 4; ++kk)
                bfr[kk] = *(const bf16x8*)(bbase + kk * 512);
            f32x4 acc = {0.f, 0.f, 0.f, 0.f};
#pragma unroll
            for (int kk = 0; kk < 4; ++kk)
                acc = __builtin_amdgcn_mfma_f32_16x16x32_bf16(bfr[kk], af[kk], acc, 0, 0, 0);
            // C layout: lane holds q = lane&15, p = p0 + (lane>>4)*4 + reg
            const float4 rpv = *(const float4*)(rp + p0 + g4);
            uint2 pk = { pack2(acc[0]*rqv*rpv.x, acc[1]*rqv*rpv.y),
                         pack2(acc[2]*rqv*rpv.z, acc[3]*rqv*rpv.w) };
            *(uint2*)&sc[w][lq][f * 16 + g4] = pk;
        }
        __syncthreads();
        // ---- flush: wave w owns rows w*4..w*4+3; per row, 4 slices (s=0..3)
        // = 4 back-to-back 1KB NT stores = one 4KB contiguous run ----
        const int fb = pblock + fl * 1024;
#pragma unroll
        for (int r4 = 0; r4 < 4; ++r4) {
            const int r = w * 4 + r4;
            float* orow = ocos + (size_t)(qrow_base + r) * Pn + fb;
#pragma unroll
            for (int s = 0; s < 4; ++s) {
                uint2 u = *(const uint2*)&sc[s][r][lane * 4];
                f32x4 vc = { __builtin_bit_cast(float, u.x << 16),
                             __builtin_bit_cast(float, u.x & 0xffff0000u),
                             __builtin_bit_cast(float, u.y << 16),
                             __builtin_bit_cast(float, u.y & 0xffff0000u) };
                __builtin_nontemporal_store(vc, (f32x4*)(orow + s * 256 + lane * 4));
            }
        }
        __syncthreads();
    }
}

extern "C" void kernel_launch(void* const* d_in, const int* in_sizes, int n_in,
                              void* d_out, int out_size, void* d_ws, size_t ws_size,
                              hipStream_t stream) {
    const int*   qid = (const int*)d_in[0];
    const int*   pid = (const int*)d_in[1];
    const float* qe  = (const float*)d_in[2];
    const float* pe  = (const float*)d_in[3];
    const int Q  = in_sizes[0];   // 4096
    const int Pn = in_sizes[1];   // 16384

    unsigned short* Qf = (unsigned short*)d_ws;
    unsigned short* Pf = Qf + (size_t)Q * 128;
    float* rq = (float*)(Pf + (size_t)Pn * 128);
    float* rp = rq + Q;

    float* oxor = (float*)d_out;
    float* ocos = oxor + (size_t)Q * (size_t)Pn;

    const int qgroups = Q / 16, pgroups = Pn / 16;
    prep_all<<<qgroups + pgroups, 256, 0, stream>>>(qe, pe, Qf, Pf, rq, rp, qgroups);

    int lg = 0; while ((1 << lg) != Pn / 4) ++lg;
    const int total4 = (int)((size_t)Q * Pn / 4);
    xor_stream<<<2048, 256, 0, stream>>>(qid, pid, oxor, total4, lg);

    const int nblocks = (Q / 16) * (Pn / PBLK);   // 2048
    cos_gemm<<<nblocks, 256, 0, stream>>>(Qf, Pf, rq, rp, ocos, Pn);
}

// Round 20
// 125.193 us; speedup vs baseline: 1.0357x; 1.0357x over previous
//
#include <hip/hip_runtime.h>
#include <stdint.h>

typedef __attribute__((ext_vector_type(8))) short bf16x8;
typedef __attribute__((ext_vector_type(4))) float f32x4;

__device__ __forceinline__ uint32_t f2bf(float f) {
    uint32_t u = __builtin_bit_cast(uint32_t, f);
    u += 0x7fffu + ((u >> 16) & 1u);   // RNE round to bf16
    return u >> 16;
}
__device__ __forceinline__ uint32_t pack2(float a, float b) {
    return f2bf(a) | (f2bf(b) << 16);
}

// Dispatch 1 of 2: prep (blocks 0..nprep-1) AND xor stream (blocks nprep..)
// in one kernel -- they are independent (xor needs only qid/pid), so the tiny
// prep blocks co-schedule under the xor streamers and cost ~zero wall time.
__global__ __launch_bounds__(256) void prep_and_xor(
        const float* __restrict__ qe, const float* __restrict__ pe,
        unsigned short* __restrict__ Qf, unsigned short* __restrict__ Pf,
        float* __restrict__ rq, float* __restrict__ rp,
        const int* __restrict__ qid, const int* __restrict__ pid,
        float* __restrict__ oxor,
        int qgroups, int nprep, int total4, int pmask_log2) {
    __shared__ float part[16][17];
    const int bid = blockIdx.x;

    if (bid < nprep) {
        // ---- prep: fp32 [rows][128] -> bf16 fragment order + recip norms ----
        const int rem = threadIdx.x;
        const bool isQ = bid < qgroups;
        const int g = isQ ? bid : bid - qgroups;
        const float* src = isQ ? qe : pe;
        unsigned short* dst = isQ ? Qf : Pf;

        const int c = rem >> 6, lane = rem & 63;
        const int rowl = lane & 15;
        const int hi = lane >> 4;
        const int row = g * 16 + rowl;
        const int col = c * 32 + hi * 8;
        const float* s = src + (size_t)row * 128 + col;
        float4 a0 = *(const float4*)s;
        float4 a1 = *(const float4*)(s + 4);
        uint4 pk = { pack2(a0.x, a0.y), pack2(a0.z, a0.w),
                     pack2(a1.x, a1.y), pack2(a1.z, a1.w) };
        *(uint4*)(dst + ((size_t)g * 256 + rem) * 8) = pk;

        float ssq = a0.x*a0.x + a0.y*a0.y + a0.z*a0.z + a0.w*a0.w
                  + a1.x*a1.x + a1.y*a1.y + a1.z*a1.z + a1.w*a1.w;
        part[rowl][c * 4 + hi] = ssq;
        __syncthreads();
        if (rem < 16) {
            float s16 = 0.f;
#pragma unroll
            for (int j = 0; j < 16; ++j) s16 += part[rem][j];
            float r = 1.0f / fmaxf(sqrtf(s16), 1e-8f);
            (isQ ? rq : rp)[g * 16 + rem] = r;
        }
        return;
    }

    // ---- xor stream: linear walk, 1KB/wave-instr NT stores (~6.5 TB/s) ----
    const int xb = bid - nprep;
    const int stride = 2048 * 256;
    int idx = xb * 256 + (int)threadIdx.x;
    const int pmask = (1 << pmask_log2) - 1;
    for (; idx < total4; idx += stride) {
        const int q = idx >> pmask_log2;
        const int pi = (idx & pmask) << 2;
        const int qv = qid[q];
        const int4 pv = *(const int4*)(pid + pi);
        f32x4 x = { pv.x == qv ? 1.f : 0.f, pv.y == qv ? 1.f : 0.f,
                    pv.z == qv ? 1.f : 0.f, pv.w == qv ? 1.f : 0.f };
        __builtin_nontemporal_store(x, (f32x4*)(oxor + ((size_t)idx << 2)));
    }
}

#define PBLK 2048   // p extent per block

// Dispatch 2 of 2: cos GEMM, R14-verbatim (best measured): zero barriers,
// wave-private 16x64p LDS transpose (stride 68), 256B row-contiguous NT stores.
__global__ __launch_bounds__(256, 4) void cos_gemm(
        const unsigned short* __restrict__ Qf, const unsigned short* __restrict__ Pf,
        const float* __restrict__ rq, const float* __restrict__ rp,
        float* __restrict__ ocos, int Pn) {
    __shared__ __align__(16) float scos[4][16][68];   // 17.4KB -> 4 blocks/CU

    const int nwg = gridDim.x;
    const int chunk = nwg >> 3;
    const int bid = blockIdx.x;
    const int wg = (bid & 7) * chunk + (bid >> 3);   // bijective XCD chunking
    const int nPc = Pn / PBLK;
    const int qg = wg / nPc;
    const int pc = wg % nPc;
    const int pblock = pc * PBLK;

    const int t = threadIdx.x;
    const int lane = t & 63;
    const int w = t >> 6;
    const int lq = lane & 15;
    const int g4 = (lane >> 4) << 2;   // 0,4,8,12

    // A fragments: coalesced 1KB loads
    bf16x8 af[4];
    const unsigned short* abase = Qf + (size_t)qg * 2048 + lane * 8;
#pragma unroll
    for (int kk = 0; kk < 4; ++kk)
        af[kk] = *(const bf16x8*)(abase + kk * 512);

    const int qrow_base = qg * 16;
    const float rqv = rq[qrow_base + lq];

#pragma unroll 1
    for (int fl = 0; fl < PBLK / 256; ++fl) {
        const int pw = pblock + fl * 256 + w * 64;   // this wave's 64p span
#pragma unroll
        for (int f = 0; f < 4; ++f) {
            const int p0 = pw + f * 16;
            const unsigned short* bbase = Pf + (size_t)(p0 >> 4) * 2048 + (size_t)lane * 8;
            bf16x8 bfr[4];
#pragma unroll
            for (int kk = 0; kk < 4; ++kk)
                bfr[kk] = *(const bf16x8*)(bbase + kk * 512);
            f32x4 acc = {0.f, 0.f, 0.f, 0.f};
#pragma unroll
            for (int kk = 0; kk < 4; ++kk)
                acc = __builtin_amdgcn_mfma_f32_16x16x32_bf16(bfr[kk], af[kk], acc, 0, 0, 0);
            // C layout: lane holds q = lane&15, p = p0 + (lane>>4)*4 + reg
            const float4 rpv = *(const float4*)(rp + p0 + g4);
            f32x4 c4 = { acc[0]*rqv*rpv.x, acc[1]*rqv*rpv.y,
                         acc[2]*rqv*rpv.z, acc[3]*rqv*rpv.w };
            *(f32x4*)&scos[w][lq][f * 16 + g4] = c4;
        }
        // flush (same wave, no barrier): 16 x 256B row-contiguous NT stores
#pragma unroll
        for (int r = 0; r < 16; ++r) {
            float vc = scos[w][r][lane];
            __builtin_nontemporal_store(vc,
                ocos + (size_t)(qrow_base + r) * Pn + pw + lane);
        }
    }
}

extern "C" void kernel_launch(void* const* d_in, const int* in_sizes, int n_in,
                              void* d_out, int out_size, void* d_ws, size_t ws_size,
                              hipStream_t stream) {
    const int*   qid = (const int*)d_in[0];
    const int*   pid = (const int*)d_in[1];
    const float* qe  = (const float*)d_in[2];
    const float* pe  = (const float*)d_in[3];
    const int Q  = in_sizes[0];   // 4096
    const int Pn = in_sizes[1];   // 16384

    unsigned short* Qf = (unsigned short*)d_ws;
    unsigned short* Pf = Qf + (size_t)Q * 128;
    float* rq = (float*)(Pf + (size_t)Pn * 128);
    float* rp = rq + Q;

    float* oxor = (float*)d_out;
    float* ocos = oxor + (size_t)Q * (size_t)Pn;

    const int qgroups = Q / 16, pgroups = Pn / 16;
    const int nprep = qgroups + pgroups;           // 1280

    int lg = 0; while ((1 << lg) != Pn / 4) ++lg;  // 12
    const int total4 = (int)((size_t)Q * Pn / 4);  // 16.7M

    prep_and_xor<<<nprep + 2048, 256, 0, stream>>>(
        qe, pe, Qf, Pf, rq, rp, qid, pid, oxor, qgroups, nprep, total4, lg);

    const int nblocks = (Q / 16) * (Pn / PBLK);    // 2048
    cos_gemm<<<nblocks, 256, 0, stream>>>(Qf, Pf, rq, rp, ocos, Pn);
}